// Round 3
// baseline (229.052 us; speedup 1.0000x reference)
//
#include <hip/hip_runtime.h>
#include <hip/hip_bf16.h>

// B=32, N=207, T=24, E=128, H=8, d=16, DM=64, M=32
#define Bn 32
#define Nn 207
#define Tt 24
#define Ee 128
#define Hh 8
#define Dm 64
#define Mm 32
#define NBN (Bn * Nn)                 // 6624
#define PT ((size_t)Nn * 16384)      // per-tensor Pt fragment elems

typedef __attribute__((ext_vector_type(8))) short bf16x8;
typedef __attribute__((ext_vector_type(4))) float f32x4;

__device__ __forceinline__ unsigned swz256(unsigned a) { return a ^ (((a >> 8) & 7u) << 4); }
__device__ __forceinline__ unsigned swz64(unsigned a)  { return a ^ (((a >> 7) & 3u) << 4); }
__device__ __forceinline__ unsigned f2b(float f) {
  union { float f; unsigned u; } x; x.f = f;
  unsigned u = x.u;
  return ((u + 0x7FFFu + ((u >> 16) & 1u)) >> 16) & 0xFFFFu;
}

// P[n][i][col] = sum_m p1[n*64+i/2][m] * p2[m][(i&1)*128+col] -> bf16 B-fragments:
// Pt[(((n*8+nt)*4+ks)*64 + lane)*8 + j] = P[n][ks*32+(lane>>4)*8+j][nt*16+(lane&15)]
__global__ __launch_bounds__(256) void build_P_frag3(
    const float* __restrict__ qp1, const float* __restrict__ qp2,
    const float* __restrict__ kp1, const float* __restrict__ kp2,
    const float* __restrict__ vp1, const float* __restrict__ vp2,
    unsigned short* __restrict__ Pt) {
  const int tau = blockIdx.y;
  const float* p1 = (tau == 0) ? qp1 : (tau == 1) ? kp1 : vp1;
  const float* p2 = (tau == 0) ? qp2 : (tau == 1) ? kp2 : vp2;
  unsigned short* dst = Pt + (size_t)tau * PT;
  const int bid = blockIdx.x;
  const int n = bid >> 3;
  const int r8 = bid & 7;
  const int ks = r8 >> 1;
  const int chunk = ((r8 & 1) << 1) + (threadIdx.x >> 7);
  const int col = threadIdx.x & 127;
  const int base_i = ks * 32 + chunk * 8;
  const float* p1r = p1 + (size_t)(n * 64 + (base_i >> 1)) * Mm;
  const float* p2a = p2 + col;
  const float* p2b = p2 + 128 + col;
  float acc[8] = {};
#pragma unroll
  for (int m = 0; m < Mm; ++m) {
    float a = p2a[m * 256], b = p2b[m * 256];
#pragma unroll
    for (int jj = 0; jj < 4; ++jj) {
      float pv = p1r[jj * Mm + m];
      acc[2 * jj]     = fmaf(pv, a, acc[2 * jj]);
      acc[2 * jj + 1] = fmaf(pv, b, acc[2 * jj + 1]);
    }
  }
  const int nt = col >> 4;
  const int lane = (chunk << 4) | (col & 15);
  union { unsigned short u[8]; uint4 v; } w;
#pragma unroll
  for (int j = 0; j < 8; ++j) w.u[j] = (unsigned short)f2b(acc[j]);
  *(uint4*)(dst + (size_t)(((n * 8 + nt) * 4 + ks) * 64 + lane) * 8) = w.v;
}

// W[128][64] -> bf16 B-fragments
__global__ __launch_bounds__(256) void build_W_frag(const float* __restrict__ W,
                                                    unsigned short* __restrict__ Wt) {
  for (int idx = threadIdx.x; idx < 1024; idx += 256) {
    int lane = idx & 63, ks = (idx >> 6) & 3, nt = idx >> 8;
    union { unsigned short u[8]; uint4 v; } w;
#pragma unroll
    for (int j = 0; j < 8; ++j)
      w.u[j] = (unsigned short)f2b(W[(size_t)(ks * 32 + (lane >> 4) * 8 + j) * 64 + nt * 16 + (lane & 15)]);
    *(uint4*)(Wt + (size_t)idx * 8) = w.v;
  }
}

// Kernel 1: projection GEMM. Block = (n, btile of 4 b's, tau). M=96 rows, K=128, N=128.
// 6 waves (384 thr); wave w owns m-fragment w (rows w*16..w*16+15), all 8 ntiles.
// Outputs: q/k -> [bn][24][128] bf16; v -> [bn][128][32] bf16 transposed, s=24..31 zeroed.
__global__ __launch_bounds__(384) void proj_gemm(
    const float* __restrict__ Xq, const float* __restrict__ Xk, const float* __restrict__ Xv,
    const unsigned short* __restrict__ Pt,
    unsigned short* __restrict__ Qw, unsigned short* __restrict__ Kw,
    unsigned short* __restrict__ Vw) {
  __shared__ __align__(16) char smem[24576];   // A tile: 96 x 128 bf16, swz256
  const int tau = blockIdx.y;
  const float* X = (tau == 0) ? Xq : (tau == 1) ? Xk : Xv;
  const unsigned short* Pf = Pt + (size_t)tau * PT;
  int gbl = blockIdx.x;
  int bx = (gbl & 7) * 207 + (gbl >> 3);       // bijective XCD swizzle (1656 = 8*207)
  const int n = bx >> 3, bt = bx & 7;
  const int b0 = bt * 4;
  const int tid = threadIdx.x;

  // stage 4 (b,n) tiles of x into LDS as bf16 (swz256), rows m = b_rel*24 + t
#pragma unroll
  for (int b_rel = 0; b_rel < 4; ++b_rel) {
    const float* src = X + ((size_t)(b0 + b_rel) * Nn + n) * (Tt * Ee);
#pragma unroll
    for (int i = 0; i < 2; ++i) {
      int idx = tid + 384 * i;                 // 0..767 float4s
      float4 xv = *(const float4*)(src + (size_t)idx * 4);
      unsigned a = swz256((unsigned)((b_rel * 24 + (idx >> 5)) * 256 + (idx & 31) * 8));
      uint2 pk;
      pk.x = f2b(xv.x) | (f2b(xv.y) << 16);
      pk.y = f2b(xv.z) | (f2b(xv.w) << 16);
      *(uint2*)(smem + a) = pk;
    }
  }
  __syncthreads();

  const int w = tid >> 6, lane = tid & 63, c = lane & 15, g = lane >> 4;
  const f32x4 zf = {0.f, 0.f, 0.f, 0.f};
  f32x4 acc[8] = {zf, zf, zf, zf, zf, zf, zf, zf};
#pragma unroll
  for (int ks = 0; ks < 4; ++ks) {
    bf16x8 Af = *(const bf16x8*)(smem + swz256((unsigned)((w * 16 + c) * 256 + ks * 64 + g * 16)));
#pragma unroll
    for (int ntl = 0; ntl < 8; ++ntl) {
      bf16x8 Bf = *(const bf16x8*)(Pf + (size_t)(((n * 8 + ntl) * 4 + ks) * 64 + lane) * 8);
      acc[ntl] = __builtin_amdgcn_mfma_f32_16x16x32_bf16(Af, Bf, acc[ntl], 0, 0, 0);
    }
  }

  if (tau < 2) {
    unsigned short* Yw = (tau == 0) ? Qw : Kw;
#pragma unroll
    for (int r = 0; r < 4; ++r) {
      int m = w * 16 + g * 4 + r;
      int b_rel = m / 24, t = m - b_rel * 24;
      size_t rowb = (((size_t)(b0 + b_rel) * Nn + n) * Tt + t) * Ee;
#pragma unroll
      for (int ntl = 0; ntl < 8; ++ntl)
        Yw[rowb + ntl * 16 + c] = (unsigned short)f2b(fmaxf(acc[ntl][r], 0.f));
    }
  } else {
#pragma unroll
    for (int r = 0; r < 4; ++r) {
      int m = w * 16 + g * 4 + r;
      int b_rel = m / 24, t = m - b_rel * 24;
      size_t tb = ((size_t)(b0 + b_rel) * Nn + n) * 4096;
#pragma unroll
      for (int ntl = 0; ntl < 8; ++ntl)
        Vw[tb + (size_t)(ntl * 16 + c) * 32 + t] = (unsigned short)f2b(fmaxf(acc[ntl][r], 0.f));
    }
    // zero-pad s = 24..31 (16B per (b_rel, e))
    for (int idx = tid; idx < 512; idx += 384) {
      int b_rel = idx >> 7, e = idx & 127;
      uint4 z = {0, 0, 0, 0};
      *(uint4*)(Vw + ((size_t)(b0 + b_rel) * Nn + n) * 4096 + (size_t)e * 32 + 24) = z;
    }
  }
}

// Kernel 2: attention per (b,n). 4 waves; wave wv owns heads {2wv, 2wv+1}.
// LDS: probs bf16 [8][32][32] swz64 @0 (16KB); outh bf16 [32][128] swz256 @16384 (8KB).
__global__ __launch_bounds__(256) void attn_k2(
    const unsigned short* __restrict__ Qw, const unsigned short* __restrict__ Kw,
    const unsigned short* __restrict__ Vw, const unsigned short* __restrict__ Wt,
    const float* __restrict__ bias,
    float* __restrict__ out, float* __restrict__ attn) {
  __shared__ __align__(16) char smem[24576];
  const int tid = threadIdx.x;
  const int lane = tid & 63;
  const int wv = tid >> 6;
  const int c = lane & 15;
  const int g = lane >> 4;
  const f32x4 zf = {0.f, 0.f, 0.f, 0.f};
  const bf16x8 zb = {0, 0, 0, 0, 0, 0, 0, 0};
  const int bn = blockIdx.x;
  const unsigned short* qb = Qw + (size_t)bn * 3072;
  const unsigned short* kb = Kw + (size_t)bn * 3072;
  const unsigned short* vb = Vw + (size_t)bn * 4096;

  // ---- scores: C[t][s] per head; K-dim = d(16), upper 16 zero-padded ----
  f32x4 sc[2][2][2];
#pragma unroll
  for (int hh = 0; hh < 2; ++hh) {
    int h = wv * 2 + hh;
    bf16x8 Aq[2], Bk[2];
#pragma unroll
    for (int mt = 0; mt < 2; ++mt) {
      Aq[mt] = zb;
      if (lane < 32) Aq[mt] = *(const bf16x8*)(qb + (size_t)(mt * 16 + c) * Ee + h * 16 + g * 8);
    }
#pragma unroll
    for (int st = 0; st < 2; ++st) {
      Bk[st] = zb;
      if (lane < 32) Bk[st] = *(const bf16x8*)(kb + (size_t)(st * 16 + c) * Ee + h * 16 + g * 8);
    }
#pragma unroll
    for (int mt = 0; mt < 2; ++mt)
#pragma unroll
      for (int st = 0; st < 2; ++st)
        sc[hh][mt][st] = __builtin_amdgcn_mfma_f32_16x16x32_bf16(Aq[mt], Bk[st], zf, 0, 0, 0);
  }

  // ---- softmax (causal) + attn global write + probs -> LDS ----
  {
    const size_t abase = (size_t)bn * (Hh * Tt * Tt);
#pragma unroll
    for (int hh = 0; hh < 2; ++hh) {
      int h = wv * 2 + hh;
#pragma unroll
      for (int mt = 0; mt < 2; ++mt)
#pragma unroll
        for (int r = 0; r < 4; ++r) {
          int t = mt * 16 + g * 4 + r;
          float v0 = (c <= t)      ? sc[hh][mt][0][r] * 0.25f : -1e30f;
          float v1 = (16 + c <= t) ? sc[hh][mt][1][r] * 0.25f : -1e30f;
          float m = fmaxf(v0, v1);
          m = fmaxf(m, __shfl_xor(m, 1));
          m = fmaxf(m, __shfl_xor(m, 2));
          m = fmaxf(m, __shfl_xor(m, 4));
          m = fmaxf(m, __shfl_xor(m, 8));
          float e0 = __expf(v0 - m);
          float e1 = __expf(v1 - m);
          float s2 = e0 + e1;
          s2 += __shfl_xor(s2, 1);
          s2 += __shfl_xor(s2, 2);
          s2 += __shfl_xor(s2, 4);
          s2 += __shfl_xor(s2, 8);
          float inv = 1.0f / s2;
          float p0 = e0 * inv, p1 = e1 * inv;
          if (t < 24) {
            float* ap = attn + abase + (size_t)h * (Tt * Tt) + t * Tt;
            ap[c] = p0;
            if (c < 8) ap[16 + c] = p1;
            *(unsigned short*)(smem + swz64((unsigned)(h * 2048 + t * 64 + c * 2)))        = (unsigned short)f2b(p0);
            *(unsigned short*)(smem + swz64((unsigned)(h * 2048 + t * 64 + (16 + c) * 2))) = (unsigned short)f2b(p1);
          }
        }
    }
  }
  __syncthreads();  // probs ready

  // ---- PV: A = probs (LDS), B = vT (global); C[t][d] -> outh LDS ----
  {
    f32x4 pv[2][2];
#pragma unroll
    for (int hh = 0; hh < 2; ++hh) {
      int h = wv * 2 + hh;
      bf16x8 Bv = *(const bf16x8*)(vb + (size_t)(h * 16 + c) * 32 + g * 8);
#pragma unroll
      for (int mt = 0; mt < 2; ++mt) {
        bf16x8 Ap = *(const bf16x8*)(smem + swz64((unsigned)(h * 2048 + (mt * 16 + c) * 64 + g * 16)));
        pv[hh][mt] = __builtin_amdgcn_mfma_f32_16x16x32_bf16(Ap, Bv, zf, 0, 0, 0);
      }
    }
#pragma unroll
    for (int hh = 0; hh < 2; ++hh) {
      int h = wv * 2 + hh;
#pragma unroll
      for (int mt = 0; mt < 2; ++mt)
#pragma unroll
        for (int r = 0; r < 4; ++r) {
          int t = mt * 16 + g * 4 + r;
          if (t < 24)
            *(unsigned short*)(smem + 16384 + swz256((unsigned)(t * 256 + (h * 16 + c) * 2))) =
                (unsigned short)f2b(pv[hh][mt][r]);
        }
    }
  }
  __syncthreads();  // outh ready

  // ---- out projection: wave wv owns cols wv*16+c; + bias, relu ----
  {
    f32x4 acc2[2] = {zf, zf};
#pragma unroll
    for (int ks = 0; ks < 4; ++ks) {
      bf16x8 Bw = *(const bf16x8*)(Wt + (size_t)((wv * 4 + ks) * 64 + lane) * 8);
#pragma unroll
      for (int mt = 0; mt < 2; ++mt) {
        bf16x8 Af = *(const bf16x8*)(smem + 16384 + swz256((unsigned)((mt * 16 + c) * 256 + ks * 64 + g * 16)));
        acc2[mt] = __builtin_amdgcn_mfma_f32_16x16x32_bf16(Af, Bw, acc2[mt], 0, 0, 0);
      }
    }
    int j = wv * 16 + c;
    float bj = bias[j];
    const size_t obase = (size_t)bn * (Tt * Dm);
#pragma unroll
    for (int mt = 0; mt < 2; ++mt)
#pragma unroll
      for (int r = 0; r < 4; ++r) {
        int t = mt * 16 + g * 4 + r;
        if (t < 24) out[obase + (size_t)t * Dm + j] = fmaxf(acc2[mt][r] + bj, 0.f);
      }
  }
}

extern "C" void kernel_launch(void* const* d_in, const int* in_sizes, int n_in,
                              void* d_out, int out_size, void* d_ws, size_t ws_size,
                              hipStream_t stream) {
  const float* query = (const float*)d_in[0];
  const float* key   = (const float*)d_in[1];
  const float* value = (const float*)d_in[2];
  const float* qp1 = (const float*)d_in[4];
  const float* qp2 = (const float*)d_in[5];
  const float* kp1 = (const float*)d_in[6];
  const float* kp2 = (const float*)d_in[7];
  const float* vp1 = (const float*)d_in[8];
  const float* vp2 = (const float*)d_in[9];
  const float* out_W = (const float*)d_in[10];
  const float* out_b = (const float*)d_in[11];

  unsigned short* Pt  = (unsigned short*)d_ws;        // 3*PT
  unsigned short* Wtf = Pt + 3 * PT;                  // 8192
  unsigned short* Qw  = Wtf + 8192;                   // NBN*3072
  unsigned short* Kw  = Qw + (size_t)NBN * 3072;      // NBN*3072
  unsigned short* Vw  = Kw + (size_t)NBN * 3072;      // NBN*4096

  float* out = (float*)d_out;
  float* attn = out + (size_t)NBN * Tt * Dm;

  build_P_frag3<<<dim3(Nn * 8, 3), 256, 0, stream>>>(qp1, qp2, kp1, kp2, vp1, vp2, Pt);
  build_W_frag<<<1, 256, 0, stream>>>(out_W, Wtf);
  proj_gemm<<<dim3(1656, 3), 384, 0, stream>>>(query, key, value, Pt, Qw, Kw, Vw);
  attn_k2<<<NBN, 256, 0, stream>>>(Qw, Kw, Vw, Wtf, out_b, out, attn);
}